// Round 2
// baseline (4876.369 us; speedup 1.0000x reference)
//
#include <hip/hip_runtime.h>

// ---------- types / helpers ----------
typedef short short8 __attribute__((ext_vector_type(8)));
typedef float f32x4 __attribute__((ext_vector_type(4)));

__device__ __forceinline__ float bf2f(unsigned short s) {
    unsigned int u = ((unsigned int)s) << 16;
    return __builtin_bit_cast(float, u);
}
__device__ __forceinline__ unsigned short f2bf(float f) {
    unsigned int u = __builtin_bit_cast(unsigned int, f);
    u += 0x7fffu + ((u >> 16) & 1u);
    return (unsigned short)(u >> 16);
}
__device__ __forceinline__ float sigm(float x) { return 1.0f / (1.0f + __expf(-x)); }

__device__ __forceinline__ void gload16(const void* g, void* l) {
    __builtin_amdgcn_global_load_lds((const __attribute__((address_space(1))) void*)g,
                                     (__attribute__((address_space(3))) void*)l, 16, 0, 0);
}

// ---------- kernel: fp32 -> bf16 vectorized convert ----------
__global__ void conv_bf16(const float4* __restrict__ src, ushort4* __restrict__ dst, int n4) {
    for (int i = blockIdx.x * blockDim.x + threadIdx.x; i < n4; i += gridDim.x * blockDim.x) {
        float4 v = src[i];
        ushort4 o;
        o.x = f2bf(v.x); o.y = f2bf(v.y); o.z = f2bf(v.z); o.w = f2bf(v.w);
        dst[i] = o;
    }
}

// ---------- kernel: transpose+convert 9 weight matrices to bf16 [N][K] ----------
struct PackArgs { const float* src[9]; };

__global__ __launch_bounds__(256) void pack_w(PackArgs pa,
                                              unsigned short* __restrict__ Wx,
                                              unsigned short* __restrict__ Wh,
                                              unsigned short* __restrict__ Wyt) {
    __shared__ float tile[32][33];
    const int z = blockIdx.z;
    const float* S = pa.src[z];
    unsigned short* D = (z < 4) ? Wx + (long)z * 1048576
                                : (z < 8) ? Wh + (long)(z - 4) * 1048576
                                          : Wyt;
    const int tx = threadIdx.x & 31, ty = threadIdx.x >> 5;
    const int rb = blockIdx.y * 32, cb = blockIdx.x * 32;
#pragma unroll
    for (int rr = 0; rr < 4; ++rr) {
        int r = ty + rr * 8;
        tile[r][tx] = S[(long)(rb + r) * 1024 + cb + tx];
    }
    __syncthreads();
#pragma unroll
    for (int rr = 0; rr < 4; ++rr) {
        int r = ty + rr * 8;
        D[(long)(cb + r) * 1024 + rb + tx] = f2bf(tile[tx][r]);
    }
}

// ---------- kernel: small init (bias concat, h0->bf16, barrier ctr=0) ----------
__global__ void init_small(const float* __restrict__ h0,
                           const float* __restrict__ bf_, const float* __restrict__ bi_,
                           const float* __restrict__ bc_, const float* __restrict__ bo_,
                           unsigned short* __restrict__ hbuf0,
                           float* __restrict__ bcat, unsigned int* __restrict__ ctr) {
    int i = blockIdx.x * blockDim.x + threadIdx.x;
    if (i == 0) *ctr = 0u;
    if (i < 65536) hbuf0[i] = f2bf(h0[i]);
    if (i < 4096) {
        const float* bs = (i < 1024) ? bf_ : (i < 2048) ? bi_ : (i < 3072) ? bc_ : bo_;
        bcat[i] = bs[i & 1023];
    }
}

// ---------- kernel: 128x128 bf16 MFMA GEMM, A[M][K] x B^T[N][K] + bias ----------
template <int OUT_BF16>
__global__ __launch_bounds__(256) void gemm_bt(const unsigned short* __restrict__ A,
                                               const unsigned short* __restrict__ B,
                                               const float* __restrict__ bias,
                                               void* __restrict__ Cout,
                                               int M, int N, int K) {
    __shared__ unsigned short As[128 * 32];
    __shared__ unsigned short Bs[128 * 32];
    const int l = threadIdx.x;
    const int w = l >> 6, u = l & 63;
    const int wr = w >> 1, wc = w & 1;
    const long rowbase = (long)blockIdx.y * 128;
    const long colbase = (long)blockIdx.x * 128;

    f32x4 acc[4][4] = {};

    const int srow = l >> 2;
    const int sunit = l & 3;

    for (int k0 = 0; k0 < K; k0 += 32) {
#pragma unroll
        for (int i = 0; i < 2; ++i) {
            int row = i * 64 + srow;
            int su = sunit ^ (row & 3);
            gload16(&A[(rowbase + row) * K + k0 + su * 8], &As[i * 2048 + l * 8]);
            gload16(&B[(colbase + row) * K + k0 + su * 8], &Bs[i * 2048 + l * 8]);
        }
        __syncthreads();
        short8 a[4], b[4];
#pragma unroll
        for (int mi = 0; mi < 4; ++mi) {
            int row = wr * 64 + mi * 16 + (u & 15);
            a[mi] = *(const short8*)&As[row * 32 + (((u >> 4) ^ (row & 3))) * 8];
        }
#pragma unroll
        for (int ni = 0; ni < 4; ++ni) {
            int row = wc * 64 + ni * 16 + (u & 15);
            b[ni] = *(const short8*)&Bs[row * 32 + (((u >> 4) ^ (row & 3))) * 8];
        }
#pragma unroll
        for (int mi = 0; mi < 4; ++mi)
#pragma unroll
            for (int ni = 0; ni < 4; ++ni)
                acc[mi][ni] = __builtin_amdgcn_mfma_f32_16x16x32_bf16(a[mi], b[ni], acc[mi][ni], 0, 0, 0);
        __syncthreads();
    }

#pragma unroll
    for (int mi = 0; mi < 4; ++mi) {
#pragma unroll
        for (int ni = 0; ni < 4; ++ni) {
#pragma unroll
            for (int r = 0; r < 4; ++r) {
                long row = rowbase + wr * 64 + mi * 16 + (u >> 4) * 4 + r;
                long col = colbase + wc * 64 + ni * 16 + (u & 15);
                float v = acc[mi][ni][r] + bias[col];
                if (OUT_BF16)
                    ((unsigned short*)Cout)[row * N + col] = f2bf(v);
                else
                    ((float*)Cout)[row * N + col] = v;
            }
        }
    }
}

// ---------- kernel: persistent recurrent scan ----------
// 64 WGs x 256 thr. WG owns 16 hidden cols (= 64 gate cols). Wave w owns K-slice
// [256w, 256w+256); weights for that slice live in VGPRs (32x short8). Per step:
// MFMA partials -> LDS K-reduction -> epilogue (c in regs) -> h/H write -> grid barrier.
__global__ __launch_bounds__(256, 1) void lstm_scan(
    const unsigned short* __restrict__ Whc,   // [4096][1024] bf16 packed W^T
    const unsigned short* __restrict__ Xg,    // [16384][4096] bf16 (bias included)
    const unsigned short* __restrict__ h0bf,  // [64][1024] bf16
    unsigned short* __restrict__ H,           // [16384][1024] bf16 (doubles as h chain)
    const float* __restrict__ c0,
    float* __restrict__ out_h, float* __restrict__ out_c,
    unsigned int* __restrict__ ctr) {
    __shared__ f32x4 red[4][4][4][64];  // [m][srcwave][g][lane] = 64 KB
    const int l = threadIdx.x, w = l >> 6, u = l & 63;
    const int j0 = blockIdx.x * 16;
    const int jj = u & 15, q = u >> 4;

    // weights -> VGPRs (once): b[g][kt] for K = w*256 + kt*32 + q*8 ..+8
    short8 b[4][8];
#pragma unroll
    for (int g = 0; g < 4; ++g)
#pragma unroll
        for (int kt = 0; kt < 8; ++kt)
            b[g][kt] = *(const short8*)&Whc[(size_t)(g * 1024 + j0 + jj) * 1024 + w * 256 + kt * 32 + q * 8];

    // c -> registers (rows w*16 + q*4 + r, col j0+jj)
    float c[4];
#pragma unroll
    for (int r = 0; r < 4; ++r)
        c[r] = c0[(size_t)(w * 16 + q * 4 + r) * 1024 + j0 + jj];

#pragma unroll 1
    for (int t = 0; t < 256; ++t) {
        const unsigned short* hp = t ? (H + (size_t)(t - 1) * 65536) : h0bf;

        // prefetch Xg gate pre-activations for this step (independent of h)
        unsigned short xg[4][4];
#pragma unroll
        for (int g = 0; g < 4; ++g)
#pragma unroll
            for (int r = 0; r < 4; ++r)
                xg[g][r] = Xg[(size_t)(t * 64 + w * 16 + q * 4 + r) * 4096 + g * 1024 + j0 + jj];

        // partial GEMM over this wave's K-slice
        f32x4 acc[4][4] = {};
#pragma unroll
        for (int kt = 0; kt < 8; ++kt) {
            short8 a[4];
#pragma unroll
            for (int m = 0; m < 4; ++m)
                a[m] = *(const short8*)&hp[(size_t)(m * 16 + jj) * 1024 + w * 256 + kt * 32 + q * 8];
#pragma unroll
            for (int m = 0; m < 4; ++m)
#pragma unroll
                for (int g = 0; g < 4; ++g)
                    acc[m][g] = __builtin_amdgcn_mfma_f32_16x16x32_bf16(a[m], b[g][kt], acc[m][g], 0, 0, 0);
        }

        // K-reduction across waves via LDS (register-natural layout, coalesced)
#pragma unroll
        for (int m = 0; m < 4; ++m)
#pragma unroll
            for (int g = 0; g < 4; ++g)
                red[m][w][g][u] = acc[m][g];
        __syncthreads();
        f32x4 gate[4];
#pragma unroll
        for (int g = 0; g < 4; ++g) {
            gate[g] = red[w][0][g][u];
#pragma unroll
            for (int w2 = 1; w2 < 4; ++w2)
                gate[g] += red[w][w2][g][u];
        }

        // epilogue: this wave owns rows w*16..w*16+15, col j0+jj
#pragma unroll
        for (int r = 0; r < 4; ++r) {
            float F = sigm(gate[0][r] + bf2f(xg[0][r]));
            float I = sigm(gate[1][r] + bf2f(xg[1][r]));
            float Cd = tanhf(gate[2][r] + bf2f(xg[2][r]));
            float O = sigm(gate[3][r] + bf2f(xg[3][r]));
            float cn = F * c[r] + I * Cd;
            c[r] = cn;
            float hf = tanhf(cn) * O;
            int row = w * 16 + q * 4 + r;
            H[(size_t)(t * 64 + row) * 1024 + j0 + jj] = f2bf(hf);
            if (t == 255) {
                out_h[(size_t)row * 1024 + j0 + jj] = hf;
                out_c[(size_t)row * 1024 + j0 + jj] = cn;
            }
        }

        // grid barrier (skip after last step)
        if (t < 255) {
            __threadfence();   // release: drain stores, flush for cross-XCD visibility
            __syncthreads();
            if (l == 0) {
                __hip_atomic_fetch_add(ctr, 1u, __ATOMIC_RELEASE, __HIP_MEMORY_SCOPE_AGENT);
                const unsigned int tgt = 64u * (unsigned)(t + 1);
                while (__hip_atomic_load(ctr, __ATOMIC_RELAXED, __HIP_MEMORY_SCOPE_AGENT) < tgt)
                    __builtin_amdgcn_s_sleep(2);
            }
            __syncthreads();
            __threadfence();   // acquire: invalidate L1/L2 before reading new h
        }
    }
}

// ---------- launch ----------
extern "C" void kernel_launch(void* const* d_in, const int* in_sizes, int n_in,
                              void* d_out, int out_size, void* d_ws, size_t ws_size,
                              hipStream_t stream) {
    const float* steps = (const float*)d_in[0];
    const float* h0 = (const float*)d_in[1];
    const float* c0 = (const float*)d_in[2];
    const float* Wfx = (const float*)d_in[3];
    const float* Wfh = (const float*)d_in[4];
    const float* bf_ = (const float*)d_in[5];
    const float* Wix = (const float*)d_in[6];
    const float* Wih = (const float*)d_in[7];
    const float* bi_ = (const float*)d_in[8];
    const float* Wcx = (const float*)d_in[9];
    const float* Wch = (const float*)d_in[10];
    const float* bc_ = (const float*)d_in[11];
    const float* Wox = (const float*)d_in[12];
    const float* Woh = (const float*)d_in[13];
    const float* bo_ = (const float*)d_in[14];
    const float* Wy = (const float*)d_in[15];
    const float* by_ = (const float*)d_in[16];

    char* ws = (char*)d_ws;
    unsigned short* Xbf = (unsigned short*)(ws + 0L);           //  33,554,432 B
    unsigned short* Xg  = (unsigned short*)(ws + 33554432L);    // 134,217,728 B
    unsigned short* H   = (unsigned short*)(ws + 167772160L);   //  33,554,432 B
    unsigned short* Wx  = (unsigned short*)(ws + 201326592L);   //   8,388,608 B
    unsigned short* Wh  = (unsigned short*)(ws + 209715200L);   //   8,388,608 B
    unsigned short* Wyt = (unsigned short*)(ws + 218103808L);   //   2,097,152 B
    float* bcat         = (float*)(ws + 220200960L);            //      16,384 B
    unsigned short* hbuf0 = (unsigned short*)(ws + 220217344L); //     131,072 B
    unsigned int* ctr   = (unsigned int*)(ws + 220348416L);     //         256 B

    float* out_y = (float*)d_out;
    float* out_h = out_y + 16777216L;
    float* out_c = out_h + 65536L;

    // 1. convert X to bf16
    conv_bf16<<<2048, 256, 0, stream>>>((const float4*)steps, (ushort4*)Xbf, 4194304);

    // 2. transpose-pack all weights to bf16 [N][K]
    PackArgs pa;
    pa.src[0] = Wfx; pa.src[1] = Wix; pa.src[2] = Wcx; pa.src[3] = Wox;
    pa.src[4] = Wfh; pa.src[5] = Wih; pa.src[6] = Wch; pa.src[7] = Woh;
    pa.src[8] = Wy;
    pack_w<<<dim3(32, 32, 9), 256, 0, stream>>>(pa, Wx, Wh, Wyt);

    // 3. small init (h0->bf16, bias concat, barrier counter = 0)
    init_small<<<256, 256, 0, stream>>>(h0, bf_, bi_, bc_, bo_, hbuf0, bcat, ctr);

    // 4. Xg = X @ Wxcat + bcat   (M=16384, N=4096, K=1024), bf16 out
    gemm_bt<1><<<dim3(32, 128), 256, 0, stream>>>(Xbf, Wx, bcat, Xg, 16384, 4096, 1024);

    // 5. persistent recurrent scan (64 WGs, co-resident, grid barrier per step)
    lstm_scan<<<64, 256, 0, stream>>>(Wh, Xg, hbuf0, H, c0, out_h, out_c, ctr);

    // 6. Y = H @ Wy + by  (M=16384, N=1024, K=1024), fp32 out to d_out
    gemm_bt<0><<<dim3(8, 128), 256, 0, stream>>>(H, Wyt, by_, (void*)d_out, 16384, 1024, 1024);
}

// Round 3
// 2685.921 us; speedup vs baseline: 1.8155x; 1.8155x over previous
//
#include <hip/hip_runtime.h>

// ---------- types / helpers ----------
typedef short short8 __attribute__((ext_vector_type(8)));
typedef float f32x4 __attribute__((ext_vector_type(4)));

__device__ __forceinline__ float bf2f(unsigned short s) {
    unsigned int u = ((unsigned int)s) << 16;
    return __builtin_bit_cast(float, u);
}
__device__ __forceinline__ unsigned short f2bf(float f) {
    unsigned int u = __builtin_bit_cast(unsigned int, f);
    u += 0x7fffu + ((u >> 16) & 1u);
    return (unsigned short)(u >> 16);
}
__device__ __forceinline__ float sigm(float x) { return 1.0f / (1.0f + __expf(-x)); }

__device__ __forceinline__ void gload16(const void* g, void* l) {
    __builtin_amdgcn_global_load_lds((const __attribute__((address_space(1))) void*)g,
                                     (__attribute__((address_space(3))) void*)l, 16, 0, 0);
}

// ---------- kernel: fp32 -> bf16 vectorized convert ----------
__global__ void conv_bf16(const float4* __restrict__ src, ushort4* __restrict__ dst, int n4) {
    for (int i = blockIdx.x * blockDim.x + threadIdx.x; i < n4; i += gridDim.x * blockDim.x) {
        float4 v = src[i];
        ushort4 o;
        o.x = f2bf(v.x); o.y = f2bf(v.y); o.z = f2bf(v.z); o.w = f2bf(v.w);
        dst[i] = o;
    }
}

// ---------- kernel: transpose+convert 9 weight matrices to bf16 [N][K] ----------
struct PackArgs { const float* src[9]; };

__global__ __launch_bounds__(256) void pack_w(PackArgs pa,
                                              unsigned short* __restrict__ Wx,
                                              unsigned short* __restrict__ Wh,
                                              unsigned short* __restrict__ Wyt) {
    __shared__ float tile[32][33];
    const int z = blockIdx.z;
    const float* S = pa.src[z];
    unsigned short* D = (z < 4) ? Wx + (long)z * 1048576
                                : (z < 8) ? Wh + (long)(z - 4) * 1048576
                                          : Wyt;
    const int tx = threadIdx.x & 31, ty = threadIdx.x >> 5;
    const int rb = blockIdx.y * 32, cb = blockIdx.x * 32;
#pragma unroll
    for (int rr = 0; rr < 4; ++rr) {
        int r = ty + rr * 8;
        tile[r][tx] = S[(long)(rb + r) * 1024 + cb + tx];
    }
    __syncthreads();
#pragma unroll
    for (int rr = 0; rr < 4; ++rr) {
        int r = ty + rr * 8;
        D[(long)(cb + r) * 1024 + rb + tx] = f2bf(tile[tx][r]);
    }
}

// ---------- kernel: small init (bias concat, h0->bf16, barrier ctr=0) ----------
__global__ void init_small(const float* __restrict__ h0,
                           const float* __restrict__ bf_, const float* __restrict__ bi_,
                           const float* __restrict__ bc_, const float* __restrict__ bo_,
                           unsigned short* __restrict__ hbuf0,
                           float* __restrict__ bcat, unsigned int* __restrict__ ctr) {
    int i = blockIdx.x * blockDim.x + threadIdx.x;
    if (i == 0) *ctr = 0u;
    if (i < 65536) hbuf0[i] = f2bf(h0[i]);
    if (i < 4096) {
        const float* bs = (i < 1024) ? bf_ : (i < 2048) ? bi_ : (i < 3072) ? bc_ : bo_;
        bcat[i] = bs[i & 1023];
    }
}

// ---------- kernel: 128x128 bf16 MFMA GEMM, A[M][K] x B^T[N][K] + bias ----------
template <int OUT_BF16>
__global__ __launch_bounds__(256) void gemm_bt(const unsigned short* __restrict__ A,
                                               const unsigned short* __restrict__ B,
                                               const float* __restrict__ bias,
                                               void* __restrict__ Cout,
                                               int M, int N, int K) {
    __shared__ unsigned short As[128 * 32];
    __shared__ unsigned short Bs[128 * 32];
    const int l = threadIdx.x;
    const int w = l >> 6, u = l & 63;
    const int wr = w >> 1, wc = w & 1;
    const long rowbase = (long)blockIdx.y * 128;
    const long colbase = (long)blockIdx.x * 128;

    f32x4 acc[4][4] = {};

    const int srow = l >> 2;
    const int sunit = l & 3;

    for (int k0 = 0; k0 < K; k0 += 32) {
#pragma unroll
        for (int i = 0; i < 2; ++i) {
            int row = i * 64 + srow;
            int su = sunit ^ (row & 3);
            gload16(&A[(rowbase + row) * K + k0 + su * 8], &As[i * 2048 + l * 8]);
            gload16(&B[(colbase + row) * K + k0 + su * 8], &Bs[i * 2048 + l * 8]);
        }
        __syncthreads();
        short8 a[4], b[4];
#pragma unroll
        for (int mi = 0; mi < 4; ++mi) {
            int row = wr * 64 + mi * 16 + (u & 15);
            a[mi] = *(const short8*)&As[row * 32 + (((u >> 4) ^ (row & 3))) * 8];
        }
#pragma unroll
        for (int ni = 0; ni < 4; ++ni) {
            int row = wc * 64 + ni * 16 + (u & 15);
            b[ni] = *(const short8*)&Bs[row * 32 + (((u >> 4) ^ (row & 3))) * 8];
        }
#pragma unroll
        for (int mi = 0; mi < 4; ++mi)
#pragma unroll
            for (int ni = 0; ni < 4; ++ni)
                acc[mi][ni] = __builtin_amdgcn_mfma_f32_16x16x32_bf16(a[mi], b[ni], acc[mi][ni], 0, 0, 0);
        __syncthreads();
    }

#pragma unroll
    for (int mi = 0; mi < 4; ++mi) {
#pragma unroll
        for (int ni = 0; ni < 4; ++ni) {
#pragma unroll
            for (int r = 0; r < 4; ++r) {
                long row = rowbase + wr * 64 + mi * 16 + (u >> 4) * 4 + r;
                long col = colbase + wc * 64 + ni * 16 + (u & 15);
                float v = acc[mi][ni][r] + bias[col];
                if (OUT_BF16)
                    ((unsigned short*)Cout)[row * N + col] = f2bf(v);
                else
                    ((float*)Cout)[row * N + col] = v;
            }
        }
    }
}

// ---------- kernel: persistent recurrent scan (fence-free cross-XCD exchange) ----------
// 64 WGs x 256 thr. WG owns 16 hidden cols (= 64 gate cols). Wave w owns K-slice
// [256w, 256w+256); weights live in VGPRs. Per step: MFMA partials -> LDS K-reduction
// -> epilogue (c in regs) -> h write-through (sc1) -> relaxed atomic grid barrier.
// NO generic fences: avoids per-WG buffer_wbl2/buffer_inv (the R2 killer).
__global__ __launch_bounds__(256, 1) void lstm_scan(
    const unsigned short* __restrict__ Whc,   // [4096][1024] bf16 packed W^T
    const unsigned short* __restrict__ Xg,    // [16384][4096] bf16 (bias included)
    const unsigned short* __restrict__ h0bf,  // [64][1024] bf16
    unsigned short* __restrict__ H,           // [16384][1024] bf16 (h chain + Y input)
    const float* __restrict__ c0,
    float* __restrict__ out_h, float* __restrict__ out_c,
    unsigned int* __restrict__ ctr) {
    __shared__ f32x4 red[4][4][4][64];  // [m][srcwave][g][lane] = 64 KB
    const int l = threadIdx.x, w = l >> 6, u = l & 63;
    const int j0 = blockIdx.x * 16;
    const int jj = u & 15, q = u >> 4;

    // weights -> VGPRs (once): b[g][kt] for K = w*256 + kt*32 + q*8 ..+8
    short8 b[4][8];
#pragma unroll
    for (int g = 0; g < 4; ++g)
#pragma unroll
        for (int kt = 0; kt < 8; ++kt)
            b[g][kt] = *(const short8*)&Whc[(size_t)(g * 1024 + j0 + jj) * 1024 + w * 256 + kt * 32 + q * 8];

    // c -> registers (rows w*16 + q*4 + r, col j0+jj)
    float c[4];
#pragma unroll
    for (int r = 0; r < 4; ++r)
        c[r] = c0[(size_t)(w * 16 + q * 4 + r) * 1024 + j0 + jj];

#pragma unroll 1
    for (int t = 0; t < 256; ++t) {
        const unsigned short* hp = t ? (H + (size_t)(t - 1) * 65536) : h0bf;

        // prefetch Xg gate pre-activations (independent of h)
        unsigned short xg[4][4];
#pragma unroll
        for (int g = 0; g < 4; ++g)
#pragma unroll
            for (int r = 0; r < 4; ++r)
                xg[g][r] = Xg[(size_t)(t * 64 + w * 16 + q * 4 + r) * 4096 + g * 1024 + j0 + jj];

        // partial GEMM over this wave's K-slice (normal cached loads of h:
        // first touch of these addresses in-kernel -> no stale L2 line possible)
        f32x4 acc[4][4] = {};
#pragma unroll
        for (int kt = 0; kt < 8; ++kt) {
            short8 a[4];
#pragma unroll
            for (int m = 0; m < 4; ++m)
                a[m] = *(const short8*)&hp[(size_t)(m * 16 + jj) * 1024 + w * 256 + kt * 32 + q * 8];
#pragma unroll
            for (int m = 0; m < 4; ++m)
#pragma unroll
                for (int g = 0; g < 4; ++g)
                    acc[m][g] = __builtin_amdgcn_mfma_f32_16x16x32_bf16(a[m], b[g][kt], acc[m][g], 0, 0, 0);
        }

        // K-reduction across waves via LDS
#pragma unroll
        for (int m = 0; m < 4; ++m)
#pragma unroll
            for (int g = 0; g < 4; ++g)
                red[m][w][g][u] = acc[m][g];
        __syncthreads();
        f32x4 gate[4];
#pragma unroll
        for (int g = 0; g < 4; ++g) {
            gate[g] = red[w][0][g][u];
#pragma unroll
            for (int w2 = 1; w2 < 4; ++w2)
                gate[g] += red[w][w2][g][u];
        }

        // epilogue: this wave owns rows w*16..w*16+15, col j0+jj
#pragma unroll
        for (int r = 0; r < 4; ++r) {
            float F = sigm(gate[0][r] + bf2f(xg[0][r]));
            float I = sigm(gate[1][r] + bf2f(xg[1][r]));
            float Cd = tanhf(gate[2][r] + bf2f(xg[2][r]));
            float O = sigm(gate[3][r] + bf2f(xg[3][r]));
            float cn = F * c[r] + I * Cd;
            c[r] = cn;
            float hf = tanhf(cn) * O;
            int row = w * 16 + q * 4 + r;
            // write-through (sc1) store: lands at coherence point, no L2 flush needed
            __hip_atomic_store(&H[(size_t)(t * 64 + row) * 1024 + j0 + jj], f2bf(hf),
                               __ATOMIC_RELAXED, __HIP_MEMORY_SCOPE_AGENT);
            if (t == 255) {
                out_h[(size_t)row * 1024 + j0 + jj] = hf;
                out_c[(size_t)row * 1024 + j0 + jj] = cn;
            }
        }

        // relaxed grid barrier (skip after last step)
        if (t < 255) {
            asm volatile("s_waitcnt vmcnt(0)" ::: "memory");  // drain own sc1 stores
            __syncthreads();
            if (l == 0) {
                __hip_atomic_fetch_add(ctr, 1u, __ATOMIC_RELAXED, __HIP_MEMORY_SCOPE_AGENT);
                const unsigned int tgt = 64u * (unsigned)(t + 1);
                while (__hip_atomic_load(ctr, __ATOMIC_RELAXED, __HIP_MEMORY_SCOPE_AGENT) < tgt)
                    __builtin_amdgcn_s_sleep(1);
            }
            __syncthreads();
            __builtin_amdgcn_sched_barrier(0);  // keep next-step loads below the spin
        }
    }
}

// ---------- launch ----------
extern "C" void kernel_launch(void* const* d_in, const int* in_sizes, int n_in,
                              void* d_out, int out_size, void* d_ws, size_t ws_size,
                              hipStream_t stream) {
    const float* steps = (const float*)d_in[0];
    const float* h0 = (const float*)d_in[1];
    const float* c0 = (const float*)d_in[2];
    const float* Wfx = (const float*)d_in[3];
    const float* Wfh = (const float*)d_in[4];
    const float* bf_ = (const float*)d_in[5];
    const float* Wix = (const float*)d_in[6];
    const float* Wih = (const float*)d_in[7];
    const float* bi_ = (const float*)d_in[8];
    const float* Wcx = (const float*)d_in[9];
    const float* Wch = (const float*)d_in[10];
    const float* bc_ = (const float*)d_in[11];
    const float* Wox = (const float*)d_in[12];
    const float* Woh = (const float*)d_in[13];
    const float* bo_ = (const float*)d_in[14];
    const float* Wy = (const float*)d_in[15];
    const float* by_ = (const float*)d_in[16];

    char* ws = (char*)d_ws;
    unsigned short* Xbf = (unsigned short*)(ws + 0L);           //  33,554,432 B
    unsigned short* Xg  = (unsigned short*)(ws + 33554432L);    // 134,217,728 B
    unsigned short* H   = (unsigned short*)(ws + 167772160L);   //  33,554,432 B
    unsigned short* Wx  = (unsigned short*)(ws + 201326592L);   //   8,388,608 B
    unsigned short* Wh  = (unsigned short*)(ws + 209715200L);   //   8,388,608 B
    unsigned short* Wyt = (unsigned short*)(ws + 218103808L);   //   2,097,152 B
    float* bcat         = (float*)(ws + 220200960L);            //      16,384 B
    unsigned short* hbuf0 = (unsigned short*)(ws + 220217344L); //     131,072 B
    unsigned int* ctr   = (unsigned int*)(ws + 220348416L);     //         256 B

    float* out_y = (float*)d_out;
    float* out_h = out_y + 16777216L;
    float* out_c = out_h + 65536L;

    // 1. convert X to bf16
    conv_bf16<<<2048, 256, 0, stream>>>((const float4*)steps, (ushort4*)Xbf, 4194304);

    // 2. transpose-pack all weights to bf16 [N][K]
    PackArgs pa;
    pa.src[0] = Wfx; pa.src[1] = Wix; pa.src[2] = Wcx; pa.src[3] = Wox;
    pa.src[4] = Wfh; pa.src[5] = Wih; pa.src[6] = Wch; pa.src[7] = Woh;
    pa.src[8] = Wy;
    pack_w<<<dim3(32, 32, 9), 256, 0, stream>>>(pa, Wx, Wh, Wyt);

    // 3. small init (h0->bf16, bias concat, barrier counter = 0)
    init_small<<<256, 256, 0, stream>>>(h0, bf_, bi_, bc_, bo_, hbuf0, bcat, ctr);

    // 4. Xg = X @ Wxcat + bcat   (M=16384, N=4096, K=1024), bf16 out
    gemm_bt<1><<<dim3(32, 128), 256, 0, stream>>>(Xbf, Wx, bcat, Xg, 16384, 4096, 1024);

    // 5. persistent recurrent scan (64 WGs, co-resident, relaxed grid barrier per step)
    lstm_scan<<<64, 256, 0, stream>>>(Wh, Xg, hbuf0, H, c0, out_h, out_c, ctr);

    // 6. Y = H @ Wy + by  (M=16384, N=1024, K=1024), fp32 out to d_out
    gemm_bt<0><<<dim3(8, 128), 256, 0, stream>>>(H, Wyt, by_, (void*)d_out, 16384, 1024, 1024);
}

// Round 4
// 2434.789 us; speedup vs baseline: 2.0028x; 1.1031x over previous
//
#include <hip/hip_runtime.h>

// ---------- types / helpers ----------
typedef short short8 __attribute__((ext_vector_type(8)));
typedef float f32x4 __attribute__((ext_vector_type(4)));

__device__ __forceinline__ float bf2f(unsigned short s) {
    unsigned int u = ((unsigned int)s) << 16;
    return __builtin_bit_cast(float, u);
}
__device__ __forceinline__ unsigned short f2bf(float f) {
    unsigned int u = __builtin_bit_cast(unsigned int, f);
    u += 0x7fffu + ((u >> 16) & 1u);
    return (unsigned short)(u >> 16);
}
__device__ __forceinline__ float sigm(float x) { return 1.0f / (1.0f + __expf(-x)); }

__device__ __forceinline__ void gload16(const void* g, void* l) {
    __builtin_amdgcn_global_load_lds((const __attribute__((address_space(1))) void*)g,
                                     (__attribute__((address_space(3))) void*)l, 16, 0, 0);
}

// ---------- kernel: fp32 -> bf16 vectorized convert ----------
__global__ void conv_bf16(const float4* __restrict__ src, ushort4* __restrict__ dst, int n4) {
    for (int i = blockIdx.x * blockDim.x + threadIdx.x; i < n4; i += gridDim.x * blockDim.x) {
        float4 v = src[i];
        ushort4 o;
        o.x = f2bf(v.x); o.y = f2bf(v.y); o.z = f2bf(v.z); o.w = f2bf(v.w);
        dst[i] = o;
    }
}

// ---------- kernel: transpose+convert 9 weight matrices to bf16 [N][K] ----------
struct PackArgs { const float* src[9]; };

__global__ __launch_bounds__(256) void pack_w(PackArgs pa,
                                              unsigned short* __restrict__ Wx,
                                              unsigned short* __restrict__ Wh,
                                              unsigned short* __restrict__ Wyt) {
    __shared__ float tile[32][33];
    const int z = blockIdx.z;
    const float* S = pa.src[z];
    unsigned short* D = (z < 4) ? Wx + (long)z * 1048576
                                : (z < 8) ? Wh + (long)(z - 4) * 1048576
                                          : Wyt;
    const int tx = threadIdx.x & 31, ty = threadIdx.x >> 5;
    const int rb = blockIdx.y * 32, cb = blockIdx.x * 32;
#pragma unroll
    for (int rr = 0; rr < 4; ++rr) {
        int r = ty + rr * 8;
        tile[r][tx] = S[(long)(rb + r) * 1024 + cb + tx];
    }
    __syncthreads();
#pragma unroll
    for (int rr = 0; rr < 4; ++rr) {
        int r = ty + rr * 8;
        D[(long)(cb + r) * 1024 + rb + tx] = f2bf(tile[tx][r]);
    }
}

// ---------- kernel: small init (bias concat, h0->bf16, flags=0) ----------
__global__ void init_small(const float* __restrict__ h0,
                           const float* __restrict__ bf_, const float* __restrict__ bi_,
                           const float* __restrict__ bc_, const float* __restrict__ bo_,
                           unsigned short* __restrict__ hbuf0,
                           float* __restrict__ bcat, unsigned int* __restrict__ flags) {
    int i = blockIdx.x * blockDim.x + threadIdx.x;
    if (i < 1024) flags[i] = 0u;   // 64 WG flags at 16-uint (64B) stride, zeroed EVERY replay
    if (i < 65536) hbuf0[i] = f2bf(h0[i]);
    if (i < 4096) {
        const float* bs = (i < 1024) ? bf_ : (i < 2048) ? bi_ : (i < 3072) ? bc_ : bo_;
        bcat[i] = bs[i & 1023];
    }
}

// ---------- kernel: 128x128 bf16 MFMA GEMM, A[M][K] x B^T[N][K] + bias ----------
template <int OUT_BF16>
__global__ __launch_bounds__(256) void gemm_bt(const unsigned short* __restrict__ A,
                                               const unsigned short* __restrict__ B,
                                               const float* __restrict__ bias,
                                               void* __restrict__ Cout,
                                               int M, int N, int K) {
    __shared__ unsigned short As[128 * 32];
    __shared__ unsigned short Bs[128 * 32];
    const int l = threadIdx.x;
    const int w = l >> 6, u = l & 63;
    const int wr = w >> 1, wc = w & 1;
    const long rowbase = (long)blockIdx.y * 128;
    const long colbase = (long)blockIdx.x * 128;

    f32x4 acc[4][4] = {};

    const int srow = l >> 2;
    const int sunit = l & 3;

    for (int k0 = 0; k0 < K; k0 += 32) {
#pragma unroll
        for (int i = 0; i < 2; ++i) {
            int row = i * 64 + srow;
            int su = sunit ^ (row & 3);
            gload16(&A[(rowbase + row) * K + k0 + su * 8], &As[i * 2048 + l * 8]);
            gload16(&B[(colbase + row) * K + k0 + su * 8], &Bs[i * 2048 + l * 8]);
        }
        __syncthreads();
        short8 a[4], b[4];
#pragma unroll
        for (int mi = 0; mi < 4; ++mi) {
            int row = wr * 64 + mi * 16 + (u & 15);
            a[mi] = *(const short8*)&As[row * 32 + (((u >> 4) ^ (row & 3))) * 8];
        }
#pragma unroll
        for (int ni = 0; ni < 4; ++ni) {
            int row = wc * 64 + ni * 16 + (u & 15);
            b[ni] = *(const short8*)&Bs[row * 32 + (((u >> 4) ^ (row & 3))) * 8];
        }
#pragma unroll
        for (int mi = 0; mi < 4; ++mi)
#pragma unroll
            for (int ni = 0; ni < 4; ++ni)
                acc[mi][ni] = __builtin_amdgcn_mfma_f32_16x16x32_bf16(a[mi], b[ni], acc[mi][ni], 0, 0, 0);
        __syncthreads();
    }

#pragma unroll
    for (int mi = 0; mi < 4; ++mi) {
#pragma unroll
        for (int ni = 0; ni < 4; ++ni) {
#pragma unroll
            for (int r = 0; r < 4; ++r) {
                long row = rowbase + wr * 64 + mi * 16 + (u >> 4) * 4 + r;
                long col = colbase + wc * 64 + ni * 16 + (u & 15);
                float v = acc[mi][ni][r] + bias[col];
                if (OUT_BF16)
                    ((unsigned short*)Cout)[row * N + col] = f2bf(v);
                else
                    ((float*)Cout)[row * N + col] = v;
            }
        }
    }
}

// ---------- kernel: persistent recurrent scan (flag-array barrier) ----------
// 64 WGs x 256 thr. WG owns 16 hidden cols (= 64 gate cols). Wave w owns K-slice
// [256w, 256w+256); weights live in VGPRs. Per step: MFMA partials -> LDS K-reduction
// -> epilogue (c in regs) -> h write-through (sc1) -> per-WG flag store (own 64B line)
// -> wave-0 vector poll of all 64 flags. No atomic RMW, no generic fences.
__global__ __launch_bounds__(256, 1) void lstm_scan(
    const unsigned short* __restrict__ Whc,   // [4096][1024] bf16 packed W^T
    const unsigned short* __restrict__ Xg,    // [16384][4096] bf16 (bias included)
    const unsigned short* __restrict__ h0bf,  // [64][1024] bf16
    unsigned short* __restrict__ H,           // [16384][1024] bf16 (h chain + Y input)
    const float* __restrict__ c0,
    float* __restrict__ out_h, float* __restrict__ out_c,
    unsigned int* __restrict__ flags) {
    __shared__ f32x4 red[4][4][4][64];  // [m][srcwave][g][lane] = 64 KB
    const int l = threadIdx.x, w = l >> 6, u = l & 63;
    const int bid = blockIdx.x;
    const int j0 = bid * 16;
    const int jj = u & 15, q = u >> 4;

    // weights -> VGPRs (once): b[g][kt] for K = w*256 + kt*32 + q*8 ..+8
    short8 b[4][8];
#pragma unroll
    for (int g = 0; g < 4; ++g)
#pragma unroll
        for (int kt = 0; kt < 8; ++kt)
            b[g][kt] = *(const short8*)&Whc[(size_t)(g * 1024 + j0 + jj) * 1024 + w * 256 + kt * 32 + q * 8];

    // c -> registers (rows w*16 + q*4 + r, col j0+jj)
    float c[4];
#pragma unroll
    for (int r = 0; r < 4; ++r)
        c[r] = c0[(size_t)(w * 16 + q * 4 + r) * 1024 + j0 + jj];

    // Xg pre-activations for t=0
    unsigned short xg[4][4];
#pragma unroll
    for (int g = 0; g < 4; ++g)
#pragma unroll
        for (int r = 0; r < 4; ++r)
            xg[g][r] = Xg[(size_t)(0 * 64 + w * 16 + q * 4 + r) * 4096 + g * 1024 + j0 + jj];

#pragma unroll 1
    for (int t = 0; t < 256; ++t) {
        const unsigned short* hp = t ? (H + (size_t)(t - 1) * 65536) : h0bf;

        // partial GEMM over this wave's K-slice (cached loads; first in-dispatch touch)
        f32x4 acc[4][4] = {};
#pragma unroll
        for (int kt = 0; kt < 8; ++kt) {
            short8 a[4];
#pragma unroll
            for (int m = 0; m < 4; ++m)
                a[m] = *(const short8*)&hp[(size_t)(m * 16 + jj) * 1024 + w * 256 + kt * 32 + q * 8];
#pragma unroll
            for (int m = 0; m < 4; ++m)
#pragma unroll
                for (int g = 0; g < 4; ++g)
                    acc[m][g] = __builtin_amdgcn_mfma_f32_16x16x32_bf16(a[m], b[g][kt], acc[m][g], 0, 0, 0);
        }

        // K-reduction across waves via LDS
#pragma unroll
        for (int m = 0; m < 4; ++m)
#pragma unroll
            for (int g = 0; g < 4; ++g)
                red[m][w][g][u] = acc[m][g];
        __syncthreads();
        f32x4 gate[4];
#pragma unroll
        for (int g = 0; g < 4; ++g) {
            gate[g] = red[w][0][g][u];
#pragma unroll
            for (int w2 = 1; w2 < 4; ++w2)
                gate[g] += red[w][w2][g][u];
        }

        // epilogue: this wave owns rows w*16..w*16+15, col j0+jj
#pragma unroll
        for (int r = 0; r < 4; ++r) {
            float F = sigm(gate[0][r] + bf2f(xg[0][r]));
            float I = sigm(gate[1][r] + bf2f(xg[1][r]));
            float Cd = tanhf(gate[2][r] + bf2f(xg[2][r]));
            float O = sigm(gate[3][r] + bf2f(xg[3][r]));
            float cn = F * c[r] + I * Cd;
            c[r] = cn;
            float hf = tanhf(cn) * O;
            int row = w * 16 + q * 4 + r;
            // write-through (sc1): lands at coherence point, no cache maintenance
            __hip_atomic_store(&H[(size_t)(t * 64 + row) * 1024 + j0 + jj], f2bf(hf),
                               __ATOMIC_RELAXED, __HIP_MEMORY_SCOPE_AGENT);
            if (t == 255) {
                out_h[(size_t)row * 1024 + j0 + jj] = hf;
                out_c[(size_t)row * 1024 + j0 + jj] = cn;
            }
        }

        if (t < 255) {
            // drain own h stores (per-wave), then WG-wide rendezvous
            asm volatile("s_waitcnt vmcnt(0)" ::: "memory");
            __syncthreads();
            // publish: one store to our own 64B flag line
            if (l == 0)
                __hip_atomic_store(&flags[bid * 16], (unsigned)(t + 1),
                                   __ATOMIC_RELAXED, __HIP_MEMORY_SCOPE_AGENT);
            // overlap: issue next-step Xg prefetch under the barrier wait
#pragma unroll
            for (int g = 0; g < 4; ++g)
#pragma unroll
                for (int r = 0; r < 4; ++r)
                    xg[g][r] = Xg[(size_t)((t + 1) * 64 + w * 16 + q * 4 + r) * 4096 + g * 1024 + j0 + jj];
            // wave 0: single vector-load poll of all 64 flags
            if (w == 0) {
                const unsigned tgt = (unsigned)(t + 1);
                while (true) {
                    unsigned f = __hip_atomic_load(&flags[u * 16], __ATOMIC_RELAXED,
                                                   __HIP_MEMORY_SCOPE_AGENT);
                    if (__all(f >= tgt)) break;
                    __builtin_amdgcn_s_sleep(1);
                }
            }
            __syncthreads();
            __builtin_amdgcn_sched_barrier(0);
        }
    }
}

// ---------- launch ----------
extern "C" void kernel_launch(void* const* d_in, const int* in_sizes, int n_in,
                              void* d_out, int out_size, void* d_ws, size_t ws_size,
                              hipStream_t stream) {
    const float* steps = (const float*)d_in[0];
    const float* h0 = (const float*)d_in[1];
    const float* c0 = (const float*)d_in[2];
    const float* Wfx = (const float*)d_in[3];
    const float* Wfh = (const float*)d_in[4];
    const float* bf_ = (const float*)d_in[5];
    const float* Wix = (const float*)d_in[6];
    const float* Wih = (const float*)d_in[7];
    const float* bi_ = (const float*)d_in[8];
    const float* Wcx = (const float*)d_in[9];
    const float* Wch = (const float*)d_in[10];
    const float* bc_ = (const float*)d_in[11];
    const float* Wox = (const float*)d_in[12];
    const float* Woh = (const float*)d_in[13];
    const float* bo_ = (const float*)d_in[14];
    const float* Wy = (const float*)d_in[15];
    const float* by_ = (const float*)d_in[16];

    char* ws = (char*)d_ws;
    unsigned short* Xbf = (unsigned short*)(ws + 0L);           //  33,554,432 B
    unsigned short* Xg  = (unsigned short*)(ws + 33554432L);    // 134,217,728 B
    unsigned short* H   = (unsigned short*)(ws + 167772160L);   //  33,554,432 B
    unsigned short* Wx  = (unsigned short*)(ws + 201326592L);   //   8,388,608 B
    unsigned short* Wh  = (unsigned short*)(ws + 209715200L);   //   8,388,608 B
    unsigned short* Wyt = (unsigned short*)(ws + 218103808L);   //   2,097,152 B
    float* bcat         = (float*)(ws + 220200960L);            //      16,384 B
    unsigned short* hbuf0 = (unsigned short*)(ws + 220217344L); //     131,072 B
    unsigned int* flags = (unsigned int*)(ws + 220348416L);     //       4,096 B

    float* out_y = (float*)d_out;
    float* out_h = out_y + 16777216L;
    float* out_c = out_h + 65536L;

    // 1. convert X to bf16
    conv_bf16<<<2048, 256, 0, stream>>>((const float4*)steps, (ushort4*)Xbf, 4194304);

    // 2. transpose-pack all weights to bf16 [N][K]
    PackArgs pa;
    pa.src[0] = Wfx; pa.src[1] = Wix; pa.src[2] = Wcx; pa.src[3] = Wox;
    pa.src[4] = Wfh; pa.src[5] = Wih; pa.src[6] = Wch; pa.src[7] = Woh;
    pa.src[8] = Wy;
    pack_w<<<dim3(32, 32, 9), 256, 0, stream>>>(pa, Wx, Wh, Wyt);

    // 3. small init (h0->bf16, bias concat, flags = 0) — runs every replay
    init_small<<<256, 256, 0, stream>>>(h0, bf_, bi_, bc_, bo_, hbuf0, bcat, flags);

    // 4. Xg = X @ Wxcat + bcat   (M=16384, N=4096, K=1024), bf16 out
    gemm_bt<1><<<dim3(32, 128), 256, 0, stream>>>(Xbf, Wx, bcat, Xg, 16384, 4096, 1024);

    // 5. persistent recurrent scan (64 WGs, co-resident, flag-array barrier)
    lstm_scan<<<64, 256, 0, stream>>>(Wh, Xg, hbuf0, H, c0, out_h, out_c, flags);

    // 6. Y = H @ Wy + by  (M=16384, N=1024, K=1024), fp32 out to d_out
    gemm_bt<0><<<dim3(8, 128), 256, 0, stream>>>(H, Wyt, by_, (void*)d_out, 16384, 1024, 1024);
}

// Round 5
// 2408.407 us; speedup vs baseline: 2.0247x; 1.0110x over previous
//
#include <hip/hip_runtime.h>

// ---------- types / helpers ----------
typedef short short8 __attribute__((ext_vector_type(8)));
typedef float f32x4 __attribute__((ext_vector_type(4)));

__device__ __forceinline__ float bf2f(unsigned short s) {
    unsigned int u = ((unsigned int)s) << 16;
    return __builtin_bit_cast(float, u);
}
__device__ __forceinline__ unsigned short f2bf(float f) {
    unsigned int u = __builtin_bit_cast(unsigned int, f);
    u += 0x7fffu + ((u >> 16) & 1u);
    return (unsigned short)(u >> 16);
}
__device__ __forceinline__ float sigm(float x) { return 1.0f / (1.0f + __expf(-x)); }

__device__ __forceinline__ void gload16(const void* g, void* l) {
    __builtin_amdgcn_global_load_lds((const __attribute__((address_space(1))) void*)g,
                                     (__attribute__((address_space(3))) void*)l, 16, 0, 0);
}

// ---------- kernel: fp32 -> bf16 vectorized convert ----------
__global__ void conv_bf16(const float4* __restrict__ src, ushort4* __restrict__ dst, int n4) {
    for (int i = blockIdx.x * blockDim.x + threadIdx.x; i < n4; i += gridDim.x * blockDim.x) {
        float4 v = src[i];
        ushort4 o;
        o.x = f2bf(v.x); o.y = f2bf(v.y); o.z = f2bf(v.z); o.w = f2bf(v.w);
        dst[i] = o;
    }
}

// ---------- kernel: transpose+convert 9 weight matrices to bf16 [N][K] ----------
struct PackArgs { const float* src[9]; };

__global__ __launch_bounds__(256) void pack_w(PackArgs pa,
                                              unsigned short* __restrict__ Wx,
                                              unsigned short* __restrict__ Wh,
                                              unsigned short* __restrict__ Wyt) {
    __shared__ float tile[32][33];
    const int z = blockIdx.z;
    const float* S = pa.src[z];
    unsigned short* D = (z < 4) ? Wx + (long)z * 1048576
                                : (z < 8) ? Wh + (long)(z - 4) * 1048576
                                          : Wyt;
    const int tx = threadIdx.x & 31, ty = threadIdx.x >> 5;
    const int rb = blockIdx.y * 32, cb = blockIdx.x * 32;
#pragma unroll
    for (int rr = 0; rr < 4; ++rr) {
        int r = ty + rr * 8;
        tile[r][tx] = S[(long)(rb + r) * 1024 + cb + tx];
    }
    __syncthreads();
#pragma unroll
    for (int rr = 0; rr < 4; ++rr) {
        int r = ty + rr * 8;
        D[(long)(cb + r) * 1024 + rb + tx] = f2bf(tile[tx][r]);
    }
}

// ---------- kernel: small init (bias concat, h0->bf16, flags=0) ----------
__global__ void init_small(const float* __restrict__ h0,
                           const float* __restrict__ bf_, const float* __restrict__ bi_,
                           const float* __restrict__ bc_, const float* __restrict__ bo_,
                           unsigned short* __restrict__ hbuf0,
                           float* __restrict__ bcat, unsigned int* __restrict__ flags) {
    int i = blockIdx.x * blockDim.x + threadIdx.x;
    if (i < 1024) flags[i] = 0u;   // 64 WG flags at 16-uint (64B) stride, zeroed EVERY replay
    if (i < 65536) hbuf0[i] = f2bf(h0[i]);
    if (i < 4096) {
        const float* bs = (i < 1024) ? bf_ : (i < 2048) ? bi_ : (i < 3072) ? bc_ : bo_;
        bcat[i] = bs[i & 1023];
    }
}

// ---------- kernel: 128x128 bf16 MFMA GEMM, A[M][K] x B^T[N][K] + bias ----------
template <int OUT_BF16>
__global__ __launch_bounds__(256) void gemm_bt(const unsigned short* __restrict__ A,
                                               const unsigned short* __restrict__ B,
                                               const float* __restrict__ bias,
                                               void* __restrict__ Cout,
                                               int M, int N, int K) {
    __shared__ unsigned short As[128 * 32];
    __shared__ unsigned short Bs[128 * 32];
    const int l = threadIdx.x;
    const int w = l >> 6, u = l & 63;
    const int wr = w >> 1, wc = w & 1;
    const long rowbase = (long)blockIdx.y * 128;
    const long colbase = (long)blockIdx.x * 128;

    f32x4 acc[4][4] = {};

    const int srow = l >> 2;
    const int sunit = l & 3;

    for (int k0 = 0; k0 < K; k0 += 32) {
#pragma unroll
        for (int i = 0; i < 2; ++i) {
            int row = i * 64 + srow;
            int su = sunit ^ (row & 3);
            gload16(&A[(rowbase + row) * K + k0 + su * 8], &As[i * 2048 + l * 8]);
            gload16(&B[(colbase + row) * K + k0 + su * 8], &Bs[i * 2048 + l * 8]);
        }
        __syncthreads();
        short8 a[4], b[4];
#pragma unroll
        for (int mi = 0; mi < 4; ++mi) {
            int row = wr * 64 + mi * 16 + (u & 15);
            a[mi] = *(const short8*)&As[row * 32 + (((u >> 4) ^ (row & 3))) * 8];
        }
#pragma unroll
        for (int ni = 0; ni < 4; ++ni) {
            int row = wc * 64 + ni * 16 + (u & 15);
            b[ni] = *(const short8*)&Bs[row * 32 + (((u >> 4) ^ (row & 3))) * 8];
        }
#pragma unroll
        for (int mi = 0; mi < 4; ++mi)
#pragma unroll
            for (int ni = 0; ni < 4; ++ni)
                acc[mi][ni] = __builtin_amdgcn_mfma_f32_16x16x32_bf16(a[mi], b[ni], acc[mi][ni], 0, 0, 0);
        __syncthreads();
    }

#pragma unroll
    for (int mi = 0; mi < 4; ++mi) {
#pragma unroll
        for (int ni = 0; ni < 4; ++ni) {
#pragma unroll
            for (int r = 0; r < 4; ++r) {
                long row = rowbase + wr * 64 + mi * 16 + (u >> 4) * 4 + r;
                long col = colbase + wc * 64 + ni * 16 + (u & 15);
                float v = acc[mi][ni][r] + bias[col];
                if (OUT_BF16)
                    ((unsigned short*)Cout)[row * N + col] = f2bf(v);
                else
                    ((float*)Cout)[row * N + col] = v;
            }
        }
    }
}

// ---------- kernel: persistent recurrent scan ----------
// 64 WGs x 256 thr. WG owns 16 hidden cols (= 64 gate cols). Wave w owns K-slice
// [256w, 256w+256); weights in VGPRs; c in regs. Per step:
//   GEMM partial -> LDS K-reduce -> epilogue -> h via LDS re-layout -> 8B sc1 stores
//   -> per-WG epoch flag -> PER-WAVE poll of its 16 producers only.
__global__ __launch_bounds__(256, 1) void lstm_scan(
    const unsigned short* __restrict__ Whc,   // [4096][1024] bf16 packed W^T
    const unsigned short* __restrict__ Xg,    // [16384][4096] bf16 (bias included)
    const unsigned short* __restrict__ h0bf,  // [64][1024] bf16
    unsigned short* __restrict__ H,           // [16384][1024] bf16 (h chain + Y input)
    const float* __restrict__ c0,
    float* __restrict__ out_h, float* __restrict__ out_c,
    unsigned int* __restrict__ flags) {
    __shared__ f32x4 red[4][4][4][64];        // [m][srcwave][g][lane] = 64 KB
    __shared__ unsigned short hs[64 * 16];    // h tile re-layout, 2 KB
    const int l = threadIdx.x, w = l >> 6, u = l & 63;
    const int bid = blockIdx.x;
    const int j0 = bid * 16;
    const int jj = u & 15, q = u >> 4;

    // weights -> VGPRs (once): b[g][kt] for K = w*256 + kt*32 + q*8 ..+8
    short8 b[4][8];
#pragma unroll
    for (int g = 0; g < 4; ++g)
#pragma unroll
        for (int kt = 0; kt < 8; ++kt)
            b[g][kt] = *(const short8*)&Whc[(size_t)(g * 1024 + j0 + jj) * 1024 + w * 256 + kt * 32 + q * 8];

    // c -> registers (rows w*16 + q*4 + r, col j0+jj)
    float c[4];
#pragma unroll
    for (int r = 0; r < 4; ++r)
        c[r] = c0[(size_t)(w * 16 + q * 4 + r) * 1024 + j0 + jj];

    // Xg pre-activations for t=0
    unsigned short xg[4][4];
#pragma unroll
    for (int g = 0; g < 4; ++g)
#pragma unroll
        for (int r = 0; r < 4; ++r)
            xg[g][r] = Xg[(size_t)(0 * 64 + w * 16 + q * 4 + r) * 4096 + g * 1024 + j0 + jj];

    // store-phase indexing: thread stores 8B = 4 cols of one row
    const int srow_ = l >> 2, sqtr = l & 3;

#pragma unroll 1
    for (int t = 0; t < 256; ++t) {
        const unsigned short* hp = t ? (H + (size_t)(t - 1) * 65536) : h0bf;

        // partial GEMM over this wave's K-slice (cached loads; first in-dispatch touch)
        f32x4 acc[4][4] = {};
#pragma unroll
        for (int kt = 0; kt < 8; ++kt) {
            short8 a[4];
#pragma unroll
            for (int m = 0; m < 4; ++m)
                a[m] = *(const short8*)&hp[(size_t)(m * 16 + jj) * 1024 + w * 256 + kt * 32 + q * 8];
#pragma unroll
            for (int m = 0; m < 4; ++m)
#pragma unroll
                for (int g = 0; g < 4; ++g)
                    acc[m][g] = __builtin_amdgcn_mfma_f32_16x16x32_bf16(a[m], b[g][kt], acc[m][g], 0, 0, 0);
        }

        __syncthreads();  // S1: prev-step hs reads done everywhere; red free
#pragma unroll
        for (int m = 0; m < 4; ++m)
#pragma unroll
            for (int g = 0; g < 4; ++g)
                red[m][w][g][u] = acc[m][g];
        __syncthreads();  // S2: red ready
        f32x4 gate[4];
#pragma unroll
        for (int g = 0; g < 4; ++g) {
            gate[g] = red[w][0][g][u];
#pragma unroll
            for (int w2 = 1; w2 < 4; ++w2)
                gate[g] += red[w][w2][g][u];
        }

        // epilogue: this wave owns rows w*16..w*16+15, col j0+jj
#pragma unroll
        for (int r = 0; r < 4; ++r) {
            float F = sigm(gate[0][r] + bf2f(xg[0][r]));
            float I = sigm(gate[1][r] + bf2f(xg[1][r]));
            float Cd = tanhf(gate[2][r] + bf2f(xg[2][r]));
            float O = sigm(gate[3][r] + bf2f(xg[3][r]));
            float cn = F * c[r] + I * Cd;
            c[r] = cn;
            float hf = tanhf(cn) * O;
            int row = w * 16 + q * 4 + r;
            hs[row * 16 + jj] = f2bf(hf);
            if (t == 255) {
                out_h[(size_t)row * 1024 + j0 + jj] = hf;
                out_c[(size_t)row * 1024 + j0 + jj] = cn;
            }
        }
        __syncthreads();  // S3: hs ready

        // wide h publish: each thread ONE 8B agent-scope (write-through) store
        {
            unsigned long long v = *(const unsigned long long*)&hs[srow_ * 16 + sqtr * 4];
            __hip_atomic_store((unsigned long long*)&H[(size_t)(t * 64 + srow_) * 1024 + j0 + sqtr * 4],
                               v, __ATOMIC_RELAXED, __HIP_MEMORY_SCOPE_AGENT);
        }

        if (t < 255) {
            asm volatile("s_waitcnt vmcnt(0)" ::: "memory");  // own stores at coherence point
            __syncthreads();  // S4: whole WG drained
            if (l == 0)
                __hip_atomic_store(&flags[bid * 16], (unsigned)(t + 1),
                                   __ATOMIC_RELAXED, __HIP_MEMORY_SCOPE_AGENT);
            // overlap: next-step Xg prefetch under the wait
#pragma unroll
            for (int g = 0; g < 4; ++g)
#pragma unroll
                for (int r = 0; r < 4; ++r)
                    xg[g][r] = Xg[(size_t)((t + 1) * 64 + w * 16 + q * 4 + r) * 4096 + g * 1024 + j0 + jj];
            // per-wave poll: only this wave's 16 producers (WGs 16w .. 16w+15)
            {
                const unsigned tgt = (unsigned)(t + 1);
                const int p = 16 * w + jj;
                while (true) {
                    unsigned f = __hip_atomic_load(&flags[p * 16], __ATOMIC_RELAXED,
                                                   __HIP_MEMORY_SCOPE_AGENT);
                    if (__all(f >= tgt)) break;
                    __builtin_amdgcn_s_sleep(1);
                }
            }
            asm volatile("" ::: "memory");        // no hoisting h loads above poll
            __builtin_amdgcn_sched_barrier(0);
        }
    }
}

// ---------- launch ----------
extern "C" void kernel_launch(void* const* d_in, const int* in_sizes, int n_in,
                              void* d_out, int out_size, void* d_ws, size_t ws_size,
                              hipStream_t stream) {
    const float* steps = (const float*)d_in[0];
    const float* h0 = (const float*)d_in[1];
    const float* c0 = (const float*)d_in[2];
    const float* Wfx = (const float*)d_in[3];
    const float* Wfh = (const float*)d_in[4];
    const float* bf_ = (const float*)d_in[5];
    const float* Wix = (const float*)d_in[6];
    const float* Wih = (const float*)d_in[7];
    const float* bi_ = (const float*)d_in[8];
    const float* Wcx = (const float*)d_in[9];
    const float* Wch = (const float*)d_in[10];
    const float* bc_ = (const float*)d_in[11];
    const float* Wox = (const float*)d_in[12];
    const float* Woh = (const float*)d_in[13];
    const float* bo_ = (const float*)d_in[14];
    const float* Wy = (const float*)d_in[15];
    const float* by_ = (const float*)d_in[16];

    char* ws = (char*)d_ws;
    unsigned short* Xbf = (unsigned short*)(ws + 0L);           //  33,554,432 B
    unsigned short* Xg  = (unsigned short*)(ws + 33554432L);    // 134,217,728 B
    unsigned short* H   = (unsigned short*)(ws + 167772160L);   //  33,554,432 B
    unsigned short* Wx  = (unsigned short*)(ws + 201326592L);   //   8,388,608 B
    unsigned short* Wh  = (unsigned short*)(ws + 209715200L);   //   8,388,608 B
    unsigned short* Wyt = (unsigned short*)(ws + 218103808L);   //   2,097,152 B
    float* bcat         = (float*)(ws + 220200960L);            //      16,384 B
    unsigned short* hbuf0 = (unsigned short*)(ws + 220217344L); //     131,072 B
    unsigned int* flags = (unsigned int*)(ws + 220348416L);     //       4,096 B

    float* out_y = (float*)d_out;
    float* out_h = out_y + 16777216L;
    float* out_c = out_h + 65536L;

    // 1. convert X to bf16
    conv_bf16<<<2048, 256, 0, stream>>>((const float4*)steps, (ushort4*)Xbf, 4194304);

    // 2. transpose-pack all weights to bf16 [N][K]
    PackArgs pa;
    pa.src[0] = Wfx; pa.src[1] = Wix; pa.src[2] = Wcx; pa.src[3] = Wox;
    pa.src[4] = Wfh; pa.src[5] = Wih; pa.src[6] = Wch; pa.src[7] = Woh;
    pa.src[8] = Wy;
    pack_w<<<dim3(32, 32, 9), 256, 0, stream>>>(pa, Wx, Wh, Wyt);

    // 3. small init (h0->bf16, bias concat, flags = 0) — runs every replay
    init_small<<<256, 256, 0, stream>>>(h0, bf_, bi_, bc_, bo_, hbuf0, bcat, flags);

    // 4. Xg = X @ Wxcat + bcat   (M=16384, N=4096, K=1024), bf16 out
    gemm_bt<1><<<dim3(32, 128), 256, 0, stream>>>(Xbf, Wx, bcat, Xg, 16384, 4096, 1024);

    // 5. persistent recurrent scan (64 WGs, co-resident, partial-dependency sync)
    lstm_scan<<<64, 256, 0, stream>>>(Wh, Xg, hbuf0, H, c0, out_h, out_c, flags);

    // 6. Y = H @ Wy + by  (M=16384, N=1024, K=1024), fp32 out to d_out
    gemm_bt<0><<<dim3(8, 128), 256, 0, stream>>>(H, Wyt, by_, (void*)d_out, 16384, 1024, 1024);
}